// Round 1
// baseline (387.125 us; speedup 1.0000x reference)
//
#include <hip/hip_runtime.h>
#include <hip/hip_bf16.h>

typedef unsigned short u16;
typedef short bf16x8 __attribute__((ext_vector_type(8)));
typedef float f32x4 __attribute__((ext_vector_type(4)));

#define B_ 4
#define S_ 1024
#define E_ 1024
#define H_ 16
#define FF_ 4096
#define D_ 64
#define M_ 4096  /* B*S */

__device__ __forceinline__ u16 f2bf(float f) {
  unsigned int u = __builtin_bit_cast(unsigned int, f);
  u += 0x7fffu + ((u >> 16) & 1u);   // RNE
  return (u16)(u >> 16);
}

__device__ __forceinline__ void gld_lds16(const void* g, void* l) {
  __builtin_amdgcn_global_load_lds((__attribute__((address_space(1))) void*)g,
                                   (__attribute__((address_space(3))) void*)l,
                                   16, 0, 0);
}

// ---------------------------------------------------------------------------
// Weight cast+transpose: W (K x N fp32) -> Wt (N x K bf16)
// one fused launch for all 6 weights
// ---------------------------------------------------------------------------
__global__ void __launch_bounds__(256) cast_transpose_all(
    const float* __restrict__ wq, const float* __restrict__ wk,
    const float* __restrict__ wv, const float* __restrict__ wo,
    const float* __restrict__ w1, const float* __restrict__ w2,
    u16* __restrict__ wt) {
  int bid = blockIdx.x;
  const float* src; u16* dst; int K, N; int local;
  if (bid < 4096) {
    int wsel = bid >> 10; local = bid & 1023; K = 1024; N = 1024;
    src = wsel == 0 ? wq : wsel == 1 ? wk : wsel == 2 ? wv : wo;
    dst = wt + (size_t)wsel * 1024 * 1024;
  } else if (bid < 8192) {
    local = bid - 4096; K = 1024; N = 4096; src = w1;
    dst = wt + (size_t)4 * 1024 * 1024;
  } else {
    local = bid - 8192; K = 4096; N = 1024; src = w2;
    dst = wt + (size_t)8 * 1024 * 1024;
  }
  int tiles_n = N >> 5;
  int n0 = (local % tiles_n) << 5, k0 = (local / tiles_n) << 5;
  __shared__ float tl[32][33];
  int tx = threadIdx.x & 31, ty = threadIdx.x >> 5;
#pragma unroll
  for (int i = 0; i < 4; ++i)
    tl[ty + i * 8][tx] = src[(size_t)(k0 + ty + i * 8) * N + n0 + tx];
  __syncthreads();
#pragma unroll
  for (int i = 0; i < 4; ++i)
    dst[(size_t)(n0 + ty + i * 8) * K + k0 + tx] = f2bf(tl[tx][ty + i * 8]);
}

// ---------------------------------------------------------------------------
// LayerNorm: fp32 (M x 1024) -> bf16 (M x 1024). One block per row.
// ---------------------------------------------------------------------------
__global__ void __launch_bounds__(256) ln_kernel(
    const float* __restrict__ x, const float* __restrict__ g,
    const float* __restrict__ bt, u16* __restrict__ out) {
  int row = blockIdx.x, t = threadIdx.x;
  const float* xr = x + (size_t)row * 1024;
  float4 v = *(const float4*)(xr + t * 4);
  float s = v.x + v.y + v.z + v.w;
  float q = v.x * v.x + v.y * v.y + v.z * v.z + v.w * v.w;
#pragma unroll
  for (int off = 1; off < 64; off <<= 1) {
    s += __shfl_xor(s, off);
    q += __shfl_xor(q, off);
  }
  __shared__ float sb[4], qb[4];
  int w = t >> 6, l = t & 63;
  if (l == 0) { sb[w] = s; qb[w] = q; }
  __syncthreads();
  s = sb[0] + sb[1] + sb[2] + sb[3];
  q = qb[0] + qb[1] + qb[2] + qb[3];
  float mean = s * (1.f / 1024.f);
  float var = q * (1.f / 1024.f) - mean * mean;
  float rs = rsqrtf(var + 1e-5f);
  float4 gv = *(const float4*)(g + t * 4);
  float4 bv = *(const float4*)(bt + t * 4);
  ushort4 o;
  o.x = f2bf((v.x - mean) * rs * gv.x + bv.x);
  o.y = f2bf((v.y - mean) * rs * gv.y + bv.y);
  o.z = f2bf((v.z - mean) * rs * gv.z + bv.z);
  o.w = f2bf((v.w - mean) * rs * gv.w + bv.w);
  *(ushort4*)(out + (size_t)row * 1024 + t * 4) = o;
}

// ---------------------------------------------------------------------------
// GEMM core: C(128x128) = A(M x K) @ Bt(N x K)^T ; bf16 in, fp32 acc
// 256 threads = 4 waves (2x2), each wave 64x64 = 4x4 frags of 16x16x32 MFMA.
// global_load_lds staging with pre-swizzled source; XOR-swizzled ds_read_b128.
// ---------------------------------------------------------------------------
__device__ __forceinline__ void gemm_core_128(
    const u16* __restrict__ A, const u16* __restrict__ Bt, int Kdim,
    int bm, int bn, u16* ldsA, u16* ldsB, f32x4 acc[4][4]) {
  const int tid = threadIdx.x;
  const int w = tid >> 6, l = tid & 63;
  const int wm = (w >> 1) << 6, wn = (w & 1) << 6;
  const int lrow = l >> 3;           // row-octet within chunk
  const int cg = (l & 7) ^ lrow;     // pre-swizzled source col-group
  const size_t arow0 = (size_t)(bm << 7) * Kdim;
  const size_t brow0 = (size_t)(bn << 7) * Kdim;
  for (int kt = 0; kt < Kdim; kt += 64) {
#pragma unroll
    for (int i = 0; i < 4; ++i) {
      int c = (w << 2) + i;          // chunk 0..15 (1KB each)
      int row = (c << 3) + lrow;     // 0..127
      gld_lds16(A + arow0 + (size_t)row * Kdim + kt + (cg << 3), ldsA + (c << 9));
      gld_lds16(Bt + brow0 + (size_t)row * Kdim + kt + (cg << 3), ldsB + (c << 9));
    }
    __syncthreads();
    bf16x8 af[2][4], bf[2][4];
    const int rr = l & 15;
    const int kgb = l >> 4;          // k-group base 0..3
#pragma unroll
    for (int ks = 0; ks < 2; ++ks) {
      const int kg = kgb + (ks << 2);  // k-group 0..7
#pragma unroll
      for (int f = 0; f < 4; ++f) {
        int ra = wm + (f << 4) + rr;
        af[ks][f] = *(const bf16x8*)(ldsA + (ra << 6) + ((kg ^ (ra & 7)) << 3));
        int rb = wn + (f << 4) + rr;
        bf[ks][f] = *(const bf16x8*)(ldsB + (rb << 6) + ((kg ^ (rb & 7)) << 3));
      }
    }
#pragma unroll
    for (int fm = 0; fm < 4; ++fm)
#pragma unroll
      for (int fn = 0; fn < 4; ++fn)
#pragma unroll
        for (int ks = 0; ks < 2; ++ks)
          acc[fm][fn] = __builtin_amdgcn_mfma_f32_16x16x32_bf16(
              af[ks][fm], bf[ks][fn], acc[fm][fn], 0, 0, 0);
    __syncthreads();
  }
}

// C/D frag mapping: row=(l>>4)*4+j, col=l&15  (guide m89/m91 verified)
#define EPI_SETUP()                                     \
  const int w = threadIdx.x >> 6, l = threadIdx.x & 63; \
  const int wm = (w >> 1) << 6, wn = (w & 1) << 6;

// --- QKV: out bf16 in (B,H,S,D); z selects q/k/v -----------------------------
__global__ void __launch_bounds__(256) gemm_qkv(
    const u16* __restrict__ nx, const u16* __restrict__ wt,
    const float* __restrict__ bq, const float* __restrict__ bk,
    const float* __restrict__ bv, u16* __restrict__ qkv) {
  __shared__ __attribute__((aligned(16))) u16 lds[2 * 128 * 64];
  f32x4 acc[4][4];
  f32x4 zf = {0.f, 0.f, 0.f, 0.f};
#pragma unroll
  for (int a = 0; a < 4; ++a)
#pragma unroll
    for (int b = 0; b < 4; ++b) acc[a][b] = zf;
  int z = blockIdx.z;
  const u16* Bt = wt + (size_t)z * 1024 * 1024;
  const float* bias = z == 0 ? bq : z == 1 ? bk : bv;
  u16* out = qkv + (size_t)z * M_ * 1024;
  gemm_core_128(nx, Bt, 1024, blockIdx.x, blockIdx.y, lds, lds + 128 * 64, acc);
  EPI_SETUP();
#pragma unroll
  for (int fm = 0; fm < 4; ++fm)
#pragma unroll
    for (int fn = 0; fn < 4; ++fn)
#pragma unroll
      for (int j = 0; j < 4; ++j) {
        int row = (blockIdx.x << 7) + wm + (fm << 4) + ((l >> 4) << 2) + j;
        int col = (blockIdx.y << 7) + wn + (fn << 4) + (l & 15);
        float v = acc[fm][fn][j] + bias[col];
        int b = row >> 10, s = row & 1023, h = col >> 6, d = col & 63;
        out[(((size_t)(b * 16 + h) << 10) + s) * 64 + d] = f2bf(v);
      }
}

// --- Wo: x1 = x + xv@Wo + bo (fp32 out) --------------------------------------
__global__ void __launch_bounds__(256) gemm_wo(
    const u16* __restrict__ xv, const u16* __restrict__ wt,
    const float* __restrict__ bo, const float* __restrict__ xres,
    float* __restrict__ x1) {
  __shared__ __attribute__((aligned(16))) u16 lds[2 * 128 * 64];
  f32x4 acc[4][4];
  f32x4 zf = {0.f, 0.f, 0.f, 0.f};
#pragma unroll
  for (int a = 0; a < 4; ++a)
#pragma unroll
    for (int b = 0; b < 4; ++b) acc[a][b] = zf;
  gemm_core_128(xv, wt, 1024, blockIdx.x, blockIdx.y, lds, lds + 128 * 64, acc);
  EPI_SETUP();
#pragma unroll
  for (int fm = 0; fm < 4; ++fm)
#pragma unroll
    for (int fn = 0; fn < 4; ++fn)
#pragma unroll
      for (int j = 0; j < 4; ++j) {
        int row = (blockIdx.x << 7) + wm + (fm << 4) + ((l >> 4) << 2) + j;
        int col = (blockIdx.y << 7) + wn + (fn << 4) + (l & 15);
        size_t idx = ((size_t)row << 10) + col;
        x1[idx] = acc[fm][fn][j] + bo[col] + xres[idx];
      }
}

// --- W1: ff1 = gelu(h@W1 + bf1) bf16 out (M x FF) ----------------------------
__global__ void __launch_bounds__(256) gemm_w1(
    const u16* __restrict__ hb, const u16* __restrict__ wt,
    const float* __restrict__ bf1, u16* __restrict__ ff1) {
  __shared__ __attribute__((aligned(16))) u16 lds[2 * 128 * 64];
  f32x4 acc[4][4];
  f32x4 zf = {0.f, 0.f, 0.f, 0.f};
#pragma unroll
  for (int a = 0; a < 4; ++a)
#pragma unroll
    for (int b = 0; b < 4; ++b) acc[a][b] = zf;
  gemm_core_128(hb, wt, 1024, blockIdx.x, blockIdx.y, lds, lds + 128 * 64, acc);
  EPI_SETUP();
#pragma unroll
  for (int fm = 0; fm < 4; ++fm)
#pragma unroll
    for (int fn = 0; fn < 4; ++fn)
#pragma unroll
      for (int j = 0; j < 4; ++j) {
        int row = (blockIdx.x << 7) + wm + (fm << 4) + ((l >> 4) << 2) + j;
        int col = (blockIdx.y << 7) + wn + (fn << 4) + (l & 15);
        float v = acc[fm][fn][j] + bf1[col];
        float ge = 0.5f * v * (1.f + erff(v * 0.70710678118654752f));
        ff1[((size_t)row << 12) + col] = f2bf(ge);
      }
}

// --- W2: out = x1 + ff1@W2 + bf2 (fp32 out, K=4096) --------------------------
__global__ void __launch_bounds__(256) gemm_w2(
    const u16* __restrict__ ff1, const u16* __restrict__ wt,
    const float* __restrict__ bf2, const float* __restrict__ x1,
    float* __restrict__ out) {
  __shared__ __attribute__((aligned(16))) u16 lds[2 * 128 * 64];
  f32x4 acc[4][4];
  f32x4 zf = {0.f, 0.f, 0.f, 0.f};
#pragma unroll
  for (int a = 0; a < 4; ++a)
#pragma unroll
    for (int b = 0; b < 4; ++b) acc[a][b] = zf;
  gemm_core_128(ff1, wt, 4096, blockIdx.x, blockIdx.y, lds, lds + 128 * 64, acc);
  EPI_SETUP();
#pragma unroll
  for (int fm = 0; fm < 4; ++fm)
#pragma unroll
    for (int fn = 0; fn < 4; ++fn)
#pragma unroll
      for (int j = 0; j < 4; ++j) {
        int row = (blockIdx.x << 7) + wm + (fm << 4) + ((l >> 4) << 2) + j;
        int col = (blockIdx.y << 7) + wn + (fn << 4) + (l & 15);
        size_t idx = ((size_t)row << 10) + col;
        out[idx] = acc[fm][fn][j] + bf2[col] + x1[idx];
      }
}

// ---------------------------------------------------------------------------
// Flash attention with fused gnn@V.
// block = (qt, h, b); 4 waves x 16 q-rows. KV tiles of 64.
// xv[b,s,e] = (softmax(QK^T/8 masked) @ V)[q,d] + (gnn @ V)[q,d]
// ---------------------------------------------------------------------------
__global__ void __launch_bounds__(256) attn_kernel(
    const u16* __restrict__ Q, const u16* __restrict__ Km,
    const u16* __restrict__ Vm, const float* __restrict__ mask,
    const float* __restrict__ gnn, u16* __restrict__ xv) {
  const int qt = blockIdx.x, h = blockIdx.y, b = blockIdx.z;
  const int tid = threadIdx.x, w = tid >> 6, l = tid & 63;
  __shared__ __attribute__((aligned(16))) u16 k_lds[64 * 64];
  __shared__ __attribute__((aligned(16))) u16 vt_lds[64 * 64];
  __shared__ __attribute__((aligned(16))) u16 p_lds[4][16 * 64];
  const size_t hb = ((size_t)(b * 16 + h)) << 16;  // *(S*D)
  const u16* Qb = Q + hb;
  const u16* Kb = Km + hb;
  const u16* Vb = Vm + hb;
  const float* maskb = mask + ((size_t)b << 20);
  const float* gnnb = gnn + ((size_t)b << 20);
  const int q0 = (qt << 6) + (w << 4);
  const int lrow = l >> 3;
  const int cg = (l & 7) ^ lrow;
  const int kb = (l >> 4) << 3;
  u16* p_w = &p_lds[w][0];

  bf16x8 qf[2];
  {
    int qr = q0 + (l & 15);
    qf[0] = *(const bf16x8*)(Qb + ((size_t)qr << 6) + kb);
    qf[1] = *(const bf16x8*)(Qb + ((size_t)qr << 6) + kb + 32);
  }
  float run_m[4], run_l[4];
  f32x4 osoft[4], ognn[4];
  f32x4 zf = {0.f, 0.f, 0.f, 0.f};
#pragma unroll
  for (int j = 0; j < 4; ++j) { run_m[j] = -1e30f; run_l[j] = 0.f; }
#pragma unroll
  for (int f = 0; f < 4; ++f) { osoft[f] = zf; ognn[f] = zf; }

  for (int kv0 = 0; kv0 < 1024; kv0 += 64) {
    // --- stage K tile (pre-swizzled source, linear LDS dest) ---
#pragma unroll
    for (int i = 0; i < 2; ++i) {
      int c = (w << 1) + i;
      int row = (c << 3) + lrow;
      gld_lds16(Kb + (((size_t)(kv0 + row)) << 6) + (cg << 3), k_lds + (c << 9));
    }
    // --- stage V^T with XOR swizzle (reg path) ---
    {
      int kvr = tid & 63;
      int d0 = (tid >> 6) << 3;
#pragma unroll
      for (int p = 0; p < 2; ++p) {
        int dd0 = d0 + (p << 5);
        bf16x8 v8 = *(const bf16x8*)(Vb + (((size_t)(kv0 + kvr)) << 6) + dd0);
#pragma unroll
        for (int j = 0; j < 8; ++j) {
          int d = dd0 + j;
          vt_lds[(d << 6) + (kvr ^ ((d & 7) << 3))] = (u16)v8[j];
        }
      }
    }
    __syncthreads();
    // --- QK^T ---
    f32x4 sfr[4];
#pragma unroll
    for (int fn = 0; fn < 4; ++fn) {
      f32x4 sacc = zf;
#pragma unroll
      for (int ks = 0; ks < 2; ++ks) {
        int kg = (kb >> 3) + (ks << 2);
        int rk = (fn << 4) + (l & 15);
        bf16x8 kf = *(const bf16x8*)(k_lds + (rk << 6) + ((kg ^ (rk & 7)) << 3));
        sacc = __builtin_amdgcn_mfma_f32_16x16x32_bf16(qf[ks], kf, sacc, 0, 0, 0);
      }
      sfr[fn] = sacc;
    }
    // --- mask + online softmax (fp32) ---
    float pval[4][4], tm[4];
#pragma unroll
    for (int j = 0; j < 4; ++j) tm[j] = -1e30f;
#pragma unroll
    for (int fn = 0; fn < 4; ++fn)
#pragma unroll
      for (int j = 0; j < 4; ++j) {
        int qrow = q0 + ((l >> 4) << 2) + j;
        int kvc = kv0 + (fn << 4) + (l & 15);
        float mv = maskb[((size_t)qrow << 10) + kvc];
        float s = (mv == 0.f) ? -1e30f : sfr[fn][j] * 0.125f;
        pval[fn][j] = s;
        tm[j] = fmaxf(tm[j], s);
      }
#pragma unroll
    for (int j = 0; j < 4; ++j) {
#pragma unroll
      for (int off = 1; off < 16; off <<= 1) tm[j] = fmaxf(tm[j], __shfl_xor(tm[j], off));
      float newm = fmaxf(run_m[j], tm[j]);
      float sc = __expf(run_m[j] - newm);
      run_m[j] = newm;
      run_l[j] *= sc;
#pragma unroll
      for (int f = 0; f < 4; ++f) osoft[f][j] *= sc;
    }
    float rowsum[4] = {0.f, 0.f, 0.f, 0.f};
#pragma unroll
    for (int fn = 0; fn < 4; ++fn)
#pragma unroll
      for (int j = 0; j < 4; ++j) {
        float p = __expf(pval[fn][j] - run_m[j]);
        pval[fn][j] = p;
        rowsum[j] += p;
      }
#pragma unroll
    for (int j = 0; j < 4; ++j) {
#pragma unroll
      for (int off = 1; off < 16; off <<= 1) rowsum[j] += __shfl_xor(rowsum[j], off);
      run_l[j] += rowsum[j];
    }
    // --- P -> LDS (bf16, swizzled; per-wave region, no barrier needed) ---
#pragma unroll
    for (int fn = 0; fn < 4; ++fn)
#pragma unroll
      for (int j = 0; j < 4; ++j) {
        int prow = ((l >> 4) << 2) + j;
        int pcol = (fn << 4) + (l & 15);
        p_w[(prow << 6) + (pcol ^ ((prow & 7) << 3))] = f2bf(pval[fn][j]);
      }
    // --- gnn A-frags (fp32 -> bf16) ---
    bf16x8 gf[2];
    {
      int qr = q0 + (l & 15);
#pragma unroll
      for (int ks = 0; ks < 2; ++ks) {
        const float* gp = gnnb + ((size_t)qr << 10) + kv0 + kb + (ks << 5);
        float gt[8];
        *(float4*)(gt) = *(const float4*)(gp);
        *(float4*)(gt + 4) = *(const float4*)(gp + 4);
        bf16x8 t;
#pragma unroll
        for (int j = 0; j < 8; ++j) t[j] = (short)f2bf(gt[j]);
        gf[ks] = t;
      }
    }
    // --- P A-frags from LDS ---
    bf16x8 pf[2];
    {
      int pr = l & 15;
#pragma unroll
      for (int ks = 0; ks < 2; ++ks) {
        int kg = (kb >> 3) + (ks << 2);
        pf[ks] = *(const bf16x8*)(p_w + (pr << 6) + ((kg ^ (pr & 7)) << 3));
      }
    }
    // --- PV + gnnV ---
#pragma unroll
    for (int fd = 0; fd < 4; ++fd) {
      int dcol = (fd << 4) + (l & 15);
#pragma unroll
      for (int ks = 0; ks < 2; ++ks) {
        int kk = kb + (ks << 5);
        bf16x8 vf = *(const bf16x8*)(vt_lds + (dcol << 6) + (kk ^ ((dcol & 7) << 3)));
        osoft[fd] = __builtin_amdgcn_mfma_f32_16x16x32_bf16(pf[ks], vf, osoft[fd], 0, 0, 0);
        ognn[fd] = __builtin_amdgcn_mfma_f32_16x16x32_bf16(gf[ks], vf, ognn[fd], 0, 0, 0);
      }
    }
    __syncthreads();
  }
  // --- epilogue: xv[b, s, h*64 + d] ---
#pragma unroll
  for (int fd = 0; fd < 4; ++fd)
#pragma unroll
    for (int j = 0; j < 4; ++j) {
      int qrow = q0 + ((l >> 4) << 2) + j;
      int e = (h << 6) + (fd << 4) + (l & 15);
      float o = osoft[fd][j] / run_l[j] + ognn[fd][j];
      xv[(((size_t)b << 10) + qrow) * 1024 + e] = f2bf(o);
    }
}

// ---------------------------------------------------------------------------
extern "C" void kernel_launch(void* const* d_in, const int* in_sizes, int n_in,
                              void* d_out, int out_size, void* d_ws, size_t ws_size,
                              hipStream_t stream) {
  (void)in_sizes; (void)n_in; (void)out_size; (void)ws_size;
  const float* x   = (const float*)d_in[0];
  const float* mask= (const float*)d_in[1];
  const float* gnn = (const float*)d_in[2];
  const float* Wq  = (const float*)d_in[3];
  const float* bq  = (const float*)d_in[4];
  const float* Wk  = (const float*)d_in[5];
  const float* bk  = (const float*)d_in[6];
  const float* Wv  = (const float*)d_in[7];
  const float* bv  = (const float*)d_in[8];
  const float* Wo  = (const float*)d_in[9];
  const float* bo  = (const float*)d_in[10];
  const float* g1  = (const float*)d_in[11];
  const float* b1  = (const float*)d_in[12];
  const float* g2  = (const float*)d_in[13];
  const float* b2  = (const float*)d_in[14];
  const float* W1  = (const float*)d_in[15];
  const float* bf1 = (const float*)d_in[16];
  const float* W2  = (const float*)d_in[17];
  const float* bf2 = (const float*)d_in[18];
  float* out = (float*)d_out;

  char* ws = (char*)d_ws;
  const size_t MB = 1024 * 1024;
  // layout (bytes): [0,24M) weights bf16 | [24M,32M) nx | [32M,56M) QKV
  // | [56M,64M) xv (then h) | [64M,80M) x1 fp32 | ff1 overlays [24M,56M)
  u16*  wt  = (u16*)(ws);
  u16*  nx  = (u16*)(ws + 24 * MB);
  u16*  qkv = (u16*)(ws + 32 * MB);
  u16*  xv  = (u16*)(ws + 56 * MB);
  float* x1 = (float*)(ws + 64 * MB);
  u16*  hbuf= (u16*)(ws + 56 * MB);  // overlays xv (dead after Wo)
  u16*  ff1 = (u16*)(ws + 24 * MB);  // overlays nx/QKV (dead after attn)

  cast_transpose_all<<<12288, 256, 0, stream>>>(Wq, Wk, Wv, Wo, W1, W2, wt);
  ln_kernel<<<4096, 256, 0, stream>>>(x, g1, b1, nx);
  gemm_qkv<<<dim3(32, 8, 3), 256, 0, stream>>>(nx, wt, bq, bk, bv, qkv);
  attn_kernel<<<dim3(16, 16, 4), 256, 0, stream>>>(
      qkv, qkv + (size_t)4 * MB, qkv + (size_t)8 * MB, mask, gnn, xv);
  gemm_wo<<<dim3(32, 8), 256, 0, stream>>>(xv, wt + (size_t)3 * MB, bo, x, x1);
  ln_kernel<<<4096, 256, 0, stream>>>(x1, g2, b2, hbuf);
  gemm_w1<<<dim3(32, 32), 256, 0, stream>>>(hbuf, wt + (size_t)4 * MB, bf1, ff1);
  gemm_w2<<<dim3(32, 8), 256, 0, stream>>>(ff1, wt + (size_t)8 * MB, bf2, x1, out);
}